// Round 6
// baseline (388.491 us; speedup 1.0000x reference)
//
#include <hip/hip_runtime.h>
#include <stdint.h>
#include <stddef.h>

typedef unsigned short u16;
typedef unsigned int   u32;

typedef __attribute__((ext_vector_type(8))) short bf16x8;
typedef __attribute__((ext_vector_type(4))) float f32x4;

__device__ __forceinline__ float b2f(u16 u)    { return __uint_as_float(((u32)u) << 16); }
__device__ __forceinline__ u16 f2b(float f){
  u32 x = __float_as_uint(f);
  return (u16)((x + 0x7FFFu + ((x >> 16) & 1u)) >> 16);
}

// ---------------------------------------------------------------------------
// K0a: x[b][c][w] FLOAT32 -> xt[b][w][c] bf16 (fused transpose+downconvert).
// B=4, C=256, W=8192.  grid (128 w-tiles, 4 c-tiles, 4 b) x 256 thr; 64x64 tile.
// ---------------------------------------------------------------------------
__global__ __launch_bounds__(256) void k_transpose(const float* __restrict__ x, u16* __restrict__ xt){
  __shared__ u16 tile[64 * 65];
  const int wt = blockIdx.x, ct = blockIdx.y, b = blockIdx.z;
  const int W0 = wt << 6, C0 = ct << 6;
  const int t = threadIdx.x;
#pragma unroll
  for (int it = 0; it < 4; ++it){
    const int task = t + (it << 8);          // 0..1023
    const int c = task >> 4, u = task & 15;  // c<64, u<16 (float4 chunks of 64-wide row)
    const float4 d = *(const float4*)(x + ((size_t)((b << 8) + C0 + c) << 13) + W0 + (u << 2));
    const int base = c * 65 + (u << 2);
    tile[base + 0] = f2b(d.x); tile[base + 1] = f2b(d.y);
    tile[base + 2] = f2b(d.z); tile[base + 3] = f2b(d.w);
  }
  __syncthreads();
#pragma unroll
  for (int it = 0; it < 2; ++it){
    const int task = t + (it << 8);          // 0..511
    const int wr = task >> 3, cu = task & 7; // wr<64, cu<8 (8 bf16 per chunk)
    const int cb = cu << 3;
    u32 a0 = (u32)tile[(cb + 0) * 65 + wr] | ((u32)tile[(cb + 1) * 65 + wr] << 16);
    u32 a1 = (u32)tile[(cb + 2) * 65 + wr] | ((u32)tile[(cb + 3) * 65 + wr] << 16);
    u32 a2 = (u32)tile[(cb + 4) * 65 + wr] | ((u32)tile[(cb + 5) * 65 + wr] << 16);
    u32 a3 = (u32)tile[(cb + 6) * 65 + wr] | ((u32)tile[(cb + 7) * 65 + wr] << 16);
    uint4 val = make_uint4(a0, a1, a2, a3);
    *(uint4*)(xt + ((size_t)((b << 13) + W0 + wr) << 8) + C0 + cb) = val;
  }
}

// ---------------------------------------------------------------------------
// K0b: build combined weight matrix Wall[896][256] (bf16) + fp32 bias ball[896]
// from FLOAT32 inputs.  rows 0-255: w1/b1, 256-511: w2/b2, 512-767: w3/b3,
// rows 768-831: Wf/bf (fc folded conv branch), 832-895: zero pad.
// grid 896 x 256 threads.
// ---------------------------------------------------------------------------
__global__ __launch_bounds__(256) void k_build(const float* __restrict__ w1, const float* __restrict__ b1,
                                               const float* __restrict__ w2, const float* __restrict__ b2,
                                               const float* __restrict__ w3, const float* __restrict__ b3,
                                               const float* __restrict__ fcw,
                                               u16* __restrict__ Wall, float* __restrict__ ball){
  const int r = blockIdx.x, c = threadIdx.x;
  float v = 0.f, bv = 0.f;
  if (r < 256){      v = w1[(r << 8) + c];          bv = b1[r]; }
  else if (r < 512){ v = w2[((r - 256) << 8) + c];  bv = b2[r - 256]; }
  else if (r < 768){ v = w3[((r - 512) << 8) + c];  bv = b3[r - 512]; }
  else if (r < 832){
    const int d = r - 768;
    float s = 0.f, sbias = 0.f;
#pragma unroll
    for (int h = 0; h < 4; ++h){
      const int ch = (h << 6) + d;
      const float f1 = fcw[h], f2 = fcw[4 + h], f3 = fcw[8 + h];
      s     += f1 * w1[(ch << 8) + c] + f2 * w2[(ch << 8) + c] + f3 * w3[(ch << 8) + c];
      sbias += f1 * b1[ch] + f2 * b2[ch] + f3 * b3[ch];
    }
    v = s; bv = sbias;
  }
  Wall[(r << 8) + c] = f2b(v);
  if (c == 0) ball[r] = bv;
}

// ---------------------------------------------------------------------------
// K1: GEMM  qkvt[b][m][w] = Wall[m][:] . xt[b][w][:] + ball[m]  (channel-major
// output).  M=896 (7 tiles of 128), N=32768 (b,w), K=256 (BK=64).
// 256 threads = 4 waves in 2x2; each wave 64x64 via 4x4 grid of 16x16x32 MFMA.
// Epilogue THIS ROUND: transpose-stage the 128x128 bf16 tile in LDS (stride
// 132 -> quad rows land 8 banks apart: conflict-free), then contiguous 16B/lane
// stores -> full 128B lines, no partial-sector RMW.
// grid (7, 256).
// ---------------------------------------------------------------------------
__global__ __launch_bounds__(256) void gemm_qkv(const u16* __restrict__ Wall, const float* __restrict__ ball,
                                                const u16* __restrict__ xt, u16* __restrict__ qkvt){
  __shared__ __align__(16) u16 smem[16896];   // K-loop: As=smem[0:8192), Bs=smem[8192:16384); epilogue: 128x132 tile
  u16* As = smem;
  u16* Bs = smem + 8192;
  const int mt = blockIdx.x, nt = blockIdx.y;
  const int b = nt >> 6;
  const int w0 = (nt & 63) << 7;
  const int tid = threadIdx.x;
  const int wave = tid >> 6, lane = tid & 63;
  const int wy = wave >> 1, wx = wave & 1;
  const int m0 = mt << 7;
  const int quad = lane >> 4, l15 = lane & 15;
  f32x4 acc[4][4] = {};

  for (int kc = 0; kc < 256; kc += 64){
    // stage 128x64 A-tile and B-tile: 1024 16B-chunks each, 4 per thread
    uint4 ra[4], rb[4];
#pragma unroll
    for (int k = 0; k < 4; ++k){
      const int cid = tid + (k << 8);          // 0..1023
      const int row = cid >> 3, u = cid & 7;   // row<128, unit<8 (8 bf16 each)
      ra[k] = *(const uint4*)(Wall + ((m0 + row) << 8) + kc + (u << 3));
      rb[k] = *(const uint4*)(xt + (((size_t)((b << 13) + w0 + row)) << 8) + kc + (u << 3));
    }
    __syncthreads();   // previous iteration's LDS reads complete before overwrite
#pragma unroll
    for (int k = 0; k < 4; ++k){
      const int cid = tid + (k << 8);
      const int row = cid >> 3, u = cid & 7;
      *(uint4*)(As + (row << 6) + (u << 3)) = ra[k];
      *(uint4*)(Bs + (row << 6) + (u << 3)) = rb[k];
    }
    __syncthreads();
#pragma unroll
    for (int ks = 0; ks < 2; ++ks){
      bf16x8 av[4], bvv[4];
#pragma unroll
      for (int i = 0; i < 4; ++i){
        const int rowA = (wy << 6) + (i << 4) + l15;
        av[i] = *(const bf16x8*)(As + (rowA << 6) + (((ks << 2) + quad) << 3));
        const int rowB = (wx << 6) + (i << 4) + l15;
        bvv[i] = *(const bf16x8*)(Bs + (rowB << 6) + (((ks << 2) + quad) << 3));
      }
#pragma unroll
      for (int i = 0; i < 4; ++i)
#pragma unroll
        for (int j = 0; j < 4; ++j)
          acc[i][j] = __builtin_amdgcn_mfma_f32_16x16x32_bf16(av[i], bvv[j], acc[i][j], 0, 0, 0);
    }
  }

  // --- epilogue: bias + bf16-convert into LDS tile [128 m][132 stride], then
  //     contiguous full-line stores to qkvt[b][m][w]. ---
  __syncthreads();   // all MFMA-feeding LDS reads done before overwrite
#pragma unroll
  for (int i = 0; i < 4; ++i){
    const int mL = (wy << 6) + (i << 4) + (quad << 2);         // local m of rr.x
    const float4 bias = *(const float4*)(ball + m0 + mL);      // rows >=832 are zeros
#pragma unroll
    for (int j = 0; j < 4; ++j){
      const int wL = (wx << 6) + (j << 4) + l15;               // local w
      const f32x4 rr = acc[i][j];
      smem[(mL + 0) * 132 + wL] = f2b(rr.x + bias.x);
      smem[(mL + 1) * 132 + wL] = f2b(rr.y + bias.y);
      smem[(mL + 2) * 132 + wL] = f2b(rr.z + bias.z);
      smem[(mL + 3) * 132 + wL] = f2b(rr.w + bias.w);
    }
  }
  __syncthreads();
#pragma unroll
  for (int k = 0; k < 8; ++k){
    const int c = tid + (k << 8);            // 0..2047
    const int row = c >> 4, u = c & 15;      // row<128, u<16 (16B chunks)
    const int m = m0 + row;
    if (m < 832){
      const uint4 val = *(const uint4*)(smem + row * 132 + (u << 3));
      *(uint4*)(qkvt + (((size_t)(b * 832 + m)) << 13) + w0 + (u << 3)) = val;
    }
  }
}

// ---------------------------------------------------------------------------
// K2: windowed attention (K_ATT=7, reflect pad) + folded conv branch.
// Channel-major, one lane per w, one wave per 64-w chunk.  Wave-private LDS
// (64 rows x 72 with 3+3 halo) -> NO barriers at all; all 64 row-loads of a
// phase are issued up front for deep memory-level parallelism.
// grid (32 wtiles of 256, 4 heads, 4 b) x 256 threads.
// ---------------------------------------------------------------------------
__global__ __launch_bounds__(256) void attn_out(const u16* __restrict__ qkvt, const float* __restrict__ wp,
                                                const float* __restrict__ depw, const float* __restrict__ depb,
                                                const float* __restrict__ r1p, const float* __restrict__ r2p,
                                                float* __restrict__ out){
  __shared__ u16 kb[4][64][72];   // wave-private slices; 36864 B
  const int wt = blockIdx.x, h = blockIdx.y, b = blockIdx.z;
  const int t = threadIdx.x;
  const int wave = t >> 6, lane = t & 63;
  const int wbase = (wt << 8) + (wave << 6);   // wave's first w
  const int w = wbase + lane;                  // this lane's w

  const size_t qbase = ((size_t)(b * 832 + (h << 6))) << 13;
  const size_t kbase = ((size_t)(b * 832 + 256 + (h << 6))) << 13;
  const size_t vbase = ((size_t)(b * 832 + 512 + (h << 6))) << 13;
  const size_t fbase = ((size_t)(b * 832 + 768 + (h << 4))) << 13;

  int wsL = wbase - 3 + lane;  wsL = wsL < 0 ? -wsL : wsL;              // left reflect
  int wsR = wbase + 61 + lane; wsR = wsR > 8191 ? 16382 - wsR : wsR;    // right reflect
  const bool haloR = lane < 6;

  // --- phase A: stage all 64 k rows, then att[kk] = sum_d q*k, qd = sum_d q*wp ---
#pragma unroll
  for (int r = 0; r < 64; ++r){
    const u16* krow = qkvt + kbase + ((size_t)r << 13);
    kb[wave][r][lane] = krow[wsL];
    if (haloR) kb[wave][r][64 + lane] = krow[wsR];
  }
  float att[7] = {0.f,0.f,0.f,0.f,0.f,0.f,0.f};
  float qd = 0.f;
#pragma unroll
  for (int r = 0; r < 64; ++r){
    const float qv = b2f(qkvt[qbase + ((size_t)r << 13) + w]);
    qd += qv * wp[r];
#pragma unroll
    for (int kk = 0; kk < 7; ++kk)
      att[kk] += qv * b2f(kb[wave][r][lane + kk]);
  }

  // --- positional term + scale + softmax over the 7-window ---
  const float locw = -1.f + (2.f / 8191.f) * (float)w;
  float mx = -1e30f;
#pragma unroll
  for (int kk = 0; kk < 7; ++kk){
    int wr = w + kk - 3;
    wr = wr < 0 ? -wr : (wr > 8191 ? 16382 - wr : wr);
    const float lr = -1.f + (2.f / 8191.f) * (float)wr;
    att[kk] = 0.125f * (att[kk] + (locw - lr) * qd);
    mx = fmaxf(mx, att[kk]);
  }
  float p[7]; float ssum = 0.f;
#pragma unroll
  for (int kk = 0; kk < 7; ++kk){ p[kk] = __expf(att[kk] - mx); ssum += p[kk]; }
  const float inv = 1.f / ssum;
#pragma unroll
  for (int kk = 0; kk < 7; ++kk) p[kk] *= inv;

  const float r1 = r1p[0];
  const float r2 = r2p[0];

  // --- phase B: stage all 64 v rows (reuse kb; same wave => ordered), f loads,
  //     out[b][h*64+d][w] = r1*(P.V) + r2*(depw*f + depb) ---
#pragma unroll
  for (int r = 0; r < 64; ++r){
    const u16* vrow = qkvt + vbase + ((size_t)r << 13);
    kb[wave][r][lane] = vrow[wsL];
    if (haloR) kb[wave][r][64 + lane] = vrow[wsR];
  }
  float fvv[16];
#pragma unroll
  for (int u = 0; u < 16; ++u)
    fvv[u] = b2f(qkvt[fbase + ((size_t)u << 13) + w]);
#pragma unroll
  for (int r = 0; r < 64; ++r){
    float o = 0.f;
#pragma unroll
    for (int kk = 0; kk < 7; ++kk)
      o += p[kk] * b2f(kb[wave][r][lane + kk]);
    const float oc = depw[(h << 6) + r] * fvv[r >> 2] + depb[(h << 6) + r];
    out[(((size_t)((b << 8) + (h << 6) + r)) << 13) + w] = r1 * o + r2 * oc;
  }
}

// ---------------------------------------------------------------------------
// launch
// ---------------------------------------------------------------------------
extern "C" void kernel_launch(void* const* d_in, const int* in_sizes, int n_in,
                              void* d_out, int out_size, void* d_ws, size_t ws_size,
                              hipStream_t stream){
  (void)in_sizes; (void)n_in; (void)out_size; (void)ws_size;
  const float* x    = (const float*)d_in[0];
  const float* w1   = (const float*)d_in[1];
  const float* b1   = (const float*)d_in[2];
  const float* w2   = (const float*)d_in[3];
  const float* b2   = (const float*)d_in[4];
  const float* w3   = (const float*)d_in[5];
  const float* b3   = (const float*)d_in[6];
  const float* wp   = (const float*)d_in[7];
  // d_in[8] = bp : cancels analytically (pe - unfolded pe), unused
  const float* fcw  = (const float*)d_in[9];
  const float* depw = (const float*)d_in[10];
  const float* depb = (const float*)d_in[11];
  const float* r1p  = (const float*)d_in[12];
  const float* r2p  = (const float*)d_in[13];
  float* out = (float*)d_out;

  char* ws = (char*)d_ws;
  u16*   xt   = (u16*)(ws);                    // 4*8192*256*2   = 16,777,216 B
  u16*   Wall = (u16*)(ws + 16777216);         // 896*256*2      =    458,752 B
  float* ball = (float*)(ws + 17235968);       // 896*4          =      3,584 B
  u16*   qkvt = (u16*)(ws + 17239552);         // 4*832*8192*2   = 54,525,952 B  (channel-major [b][m][w])
                                               // total ~71.8 MB

  k_transpose<<<dim3(128, 4, 4), 256, 0, stream>>>(x, xt);
  k_build<<<dim3(896, 1, 1), 256, 0, stream>>>(w1, b1, w2, b2, w3, b3, fcw, Wall, ball);
  gemm_qkv<<<dim3(7, 256, 1), 256, 0, stream>>>(Wall, ball, xt, qkvt);
  attn_out<<<dim3(32, 4, 4), 256, 0, stream>>>(qkvt, wp, depw, depb, r1p, r2p, out);
}

// Round 8
// 282.096 us; speedup vs baseline: 1.3772x; 1.3772x over previous
//
#include <hip/hip_runtime.h>
#include <stdint.h>
#include <stddef.h>

typedef unsigned short u16;
typedef unsigned int   u32;

typedef __attribute__((ext_vector_type(8))) short bf16x8;
typedef __attribute__((ext_vector_type(4))) float f32x4;

__device__ __forceinline__ float b2f(u16 u)    { return __uint_as_float(((u32)u) << 16); }
__device__ __forceinline__ u16 f2b(float f){
  u32 x = __float_as_uint(f);
  return (u16)((x + 0x7FFFu + ((x >> 16) & 1u)) >> 16);
}

// ---------------------------------------------------------------------------
// K0: build combined weight matrix Wall[896][256] (bf16) + fp32 bias ball[896]
// from FLOAT32 inputs.  rows 0-255: w1/b1, 256-511: w2/b2, 512-767: w3/b3,
// rows 768-831: Wf/bf (fc folded conv branch), 832-895: zero pad.
// ---------------------------------------------------------------------------
__global__ __launch_bounds__(256) void k_build(const float* __restrict__ w1, const float* __restrict__ b1,
                                               const float* __restrict__ w2, const float* __restrict__ b2,
                                               const float* __restrict__ w3, const float* __restrict__ b3,
                                               const float* __restrict__ fcw,
                                               u16* __restrict__ Wall, float* __restrict__ ball){
  const int r = blockIdx.x, c = threadIdx.x;
  float v = 0.f, bv = 0.f;
  if (r < 256){      v = w1[(r << 8) + c];          bv = b1[r]; }
  else if (r < 512){ v = w2[((r - 256) << 8) + c];  bv = b2[r - 256]; }
  else if (r < 768){ v = w3[((r - 512) << 8) + c];  bv = b3[r - 512]; }
  else if (r < 832){
    const int d = r - 768;
    float s = 0.f, sbias = 0.f;
#pragma unroll
    for (int h = 0; h < 4; ++h){
      const int ch = (h << 6) + d;
      const float f1 = fcw[h], f2 = fcw[4 + h], f3 = fcw[8 + h];
      s     += f1 * w1[(ch << 8) + c] + f2 * w2[(ch << 8) + c] + f3 * w3[(ch << 8) + c];
      sbias += f1 * b1[ch] + f2 * b2[ch] + f3 * b3[ch];
    }
    v = s; bv = sbias;
  }
  Wall[(r << 8) + c] = f2b(v);
  if (c == 0) ball[r] = bv;
}

// ---------------------------------------------------------------------------
// K1: GEMM  qkvt[b][m][w] = Wall[m][:] . x[b][:][w] + ball[m]  (channel-major
// out).  Reads x DIRECTLY (transpose kernel eliminated): x staged as f32 LDS
// tile [64 c][132 w-stride] with 8-elem XOR swizzle (col ^ 8*((c>>3)&3));
// B-fragments built by 8 scalar f32 column reads (2-way banks = free)
// + round-to-nearest bf16 pack.  Epilogue: LDS-staged 128x132 bf16 tile ->
// full 256B-line stores.  grid (7 mt, 256 ntb) x 256 thr.
// R8 FIX: smem was 49408 B but As(16384)+Xt(64*132*4=33792) = 50176 B; the
// Xt tail (rows 62-63) overflowed -> garbage B-fragments -> absmax 0.488.
// ---------------------------------------------------------------------------
__global__ __launch_bounds__(256) void gemm_qkv(const u16* __restrict__ Wall, const float* __restrict__ ball,
                                                const float* __restrict__ x, u16* __restrict__ qkvt){
  __shared__ __align__(16) char smem_raw[50176];
  u16*   As = (u16*)smem_raw;                 // 128x64 bf16 = 16384 B
  float* Xt = (float*)(smem_raw + 16384);     // 64x132 f32  = 33792 B (swizzled)
  u16*   Ct = (u16*)smem_raw;                 // epilogue 128x132 bf16 = 33792 B (overlay)

  const int mt = blockIdx.x, nt = blockIdx.y;
  const int b = nt >> 6;
  const int w0 = (nt & 63) << 7;
  const int tid = threadIdx.x;
  const int wave = tid >> 6, lane = tid & 63;
  const int wy = wave >> 1, wx = wave & 1;
  const int m0 = mt << 7;
  const int quad = lane >> 4, l15 = lane & 15;
  f32x4 acc[4][4] = {};

  for (int kc = 0; kc < 256; kc += 64){
    // stage A (Wall 128x64 bf16): 1024 uint4, 4/thread
    uint4 ra[4];
#pragma unroll
    for (int k = 0; k < 4; ++k){
      const int id = tid + (k << 8);
      const int row = id >> 3, u = id & 7;
      ra[k] = *(const uint4*)(Wall + ((m0 + row) << 8) + kc + (u << 3));
    }
    // stage x (64 c x 128 w f32): 2048 float4, 8/thread
    float4 rx[8];
#pragma unroll
    for (int k = 0; k < 8; ++k){
      const int id = tid + (k << 8);
      const int c = id >> 5, j = id & 31;
      rx[k] = *(const float4*)(x + (((size_t)((b << 8) + kc + c)) << 13) + w0 + (j << 2));
    }
    __syncthreads();   // previous iteration's LDS reads complete
#pragma unroll
    for (int k = 0; k < 4; ++k){
      const int id = tid + (k << 8);
      const int row = id >> 3, u = id & 7;
      *(uint4*)(As + (row << 6) + (u << 3)) = ra[k];
    }
#pragma unroll
    for (int k = 0; k < 8; ++k){
      const int id = tid + (k << 8);
      const int c = id >> 5, j = id & 31;
      const int col = (j << 2) ^ (((c >> 3) & 3) << 3);
      *(float4*)(Xt + c * 132 + col) = rx[k];
    }
    __syncthreads();
#pragma unroll
    for (int ks = 0; ks < 2; ++ks){
      bf16x8 av[4], bvv[4];
#pragma unroll
      for (int i = 0; i < 4; ++i){
        const int rowA = (wy << 6) + (i << 4) + l15;
        av[i] = *(const bf16x8*)(As + (rowA << 6) + (((ks << 2) + quad) << 3));
      }
#pragma unroll
      for (int j = 0; j < 4; ++j){
        const int wL = (wx << 6) + (j << 4) + l15;
        u32 pk[4];
#pragma unroll
        for (int e2 = 0; e2 < 4; ++e2){
          const int c0 = (ks << 5) + (quad << 3) + (e2 << 1);
          const int s0 = ((c0 >> 3) & 3) << 3;            // = 8*quad
          const float v0 = Xt[c0 * 132 + (wL ^ s0)];
          const float v1 = Xt[(c0 + 1) * 132 + (wL ^ s0)];
          pk[e2] = ((__float_as_uint(v0) + 0x8000u) >> 16) |
                   ((__float_as_uint(v1) + 0x8000u) & 0xFFFF0000u);
        }
        uint4 pu = make_uint4(pk[0], pk[1], pk[2], pk[3]);
        bvv[j] = *(bf16x8*)&pu;
      }
#pragma unroll
      for (int i = 0; i < 4; ++i)
#pragma unroll
        for (int j = 0; j < 4; ++j)
          acc[i][j] = __builtin_amdgcn_mfma_f32_16x16x32_bf16(av[i], bvv[j], acc[i][j], 0, 0, 0);
    }
  }

  // --- epilogue: bias + bf16 into LDS tile [128 m][132], then full-line stores ---
  __syncthreads();
#pragma unroll
  for (int i = 0; i < 4; ++i){
    const int mL = (wy << 6) + (i << 4) + (quad << 2);
    const float4 bias = *(const float4*)(ball + m0 + mL);
#pragma unroll
    for (int j = 0; j < 4; ++j){
      const int wL = (wx << 6) + (j << 4) + l15;
      const f32x4 rr = acc[i][j];
      Ct[(mL + 0) * 132 + wL] = f2b(rr.x + bias.x);
      Ct[(mL + 1) * 132 + wL] = f2b(rr.y + bias.y);
      Ct[(mL + 2) * 132 + wL] = f2b(rr.z + bias.z);
      Ct[(mL + 3) * 132 + wL] = f2b(rr.w + bias.w);
    }
  }
  __syncthreads();
#pragma unroll
  for (int k = 0; k < 8; ++k){
    const int c = tid + (k << 8);            // 0..2047
    const int row = c >> 4, u = c & 15;
    const int m = m0 + row;
    if (m < 832){
      const uint4 val = *(const uint4*)(Ct + row * 132 + (u << 3));
      *(uint4*)(qkvt + (((size_t)(b * 832 + m)) << 13) + w0 + (u << 3)) = val;
    }
  }
}

// ---------------------------------------------------------------------------
// K2: windowed attention (K=7 reflect) + folded conv branch.  Channel-major.
// Block = (wt 256w, h, b).  Block-COOPERATIVE uint4 staging into LDS:
// k/v in d-chunks of 32 (rows [32][272] with halo, slot = w - base),
// q [32][256], f [16][256].  Compute: per-lane scalar LDS reads (2-way banks),
// 7 block barriers total, low VGPR.  grid (32,4,4) x 256.
// ---------------------------------------------------------------------------
__global__ __launch_bounds__(256) void attn_out(const u16* __restrict__ qkvt, const float* __restrict__ wp,
                                                const float* __restrict__ depw, const float* __restrict__ depb,
                                                const float* __restrict__ r1p, const float* __restrict__ r2p,
                                                float* __restrict__ out){
  __shared__ __align__(16) u16 kv[32 * 272];   // 17408 B
  __shared__ __align__(16) u16 qs[32 * 256];   // 16384 B
  __shared__ __align__(16) u16 fs[16 * 256];   //  8192 B
  const int wt = blockIdx.x, h = blockIdx.y, b = blockIdx.z;
  const int t = threadIdx.x;
  const int wq = (wt << 8) + t;                     // this thread's w
  const int base = (wt == 0) ? 0 : ((wt << 8) - 8); // buffer covers w in [base, base+272)
  const int bm = b * 832;

  int bi[7];
#pragma unroll
  for (int kk = 0; kk < 7; ++kk){
    int wsx = wq + kk - 3;
    wsx = wsx < 0 ? -wsx : (wsx > 8191 ? 16382 - wsx : wsx);
    bi[kk] = wsx - base;
  }

  float att[7] = {0.f,0.f,0.f,0.f,0.f,0.f,0.f};
  float qd = 0.f;

  // ---- phase A: d-chunks of 32: stage k+q, accumulate QK ----
  for (int ch = 0; ch < 2; ++ch){
    const int moff = ch << 5;
    __syncthreads();                         // prior chunk's reads done
#pragma unroll
    for (int k = 0; k < 4; ++k){             // k-tile main: 32 rows x 32 chunks
      const int id = t + (k << 8);
      const int r = id >> 5, c = id & 31;
      int wc = base + (c << 3); if (wc > 8184) wc = 8184;
      const uint4 d = *(const uint4*)(qkvt + (((size_t)(bm + 256 + (h << 6) + moff + r)) << 13) + wc);
      *(uint4*)(kv + r * 272 + (c << 3)) = d;
    }
    if (t < 64){                             // k-tile tail: chunks 32,33
      const int r = t >> 1, c = 32 + (t & 1);
      int wc = base + (c << 3); if (wc > 8184) wc = 8184;
      const uint4 d = *(const uint4*)(qkvt + (((size_t)(bm + 256 + (h << 6) + moff + r)) << 13) + wc);
      *(uint4*)(kv + r * 272 + (c << 3)) = d;
    }
#pragma unroll
    for (int k = 0; k < 4; ++k){             // q-tile: 32 rows x 32 chunks
      const int id = t + (k << 8);
      const int r = id >> 5, c = id & 31;
      const uint4 d = *(const uint4*)(qkvt + (((size_t)(bm + (h << 6) + moff + r)) << 13) + (wt << 8) + (c << 3));
      *(uint4*)(qs + (r << 8) + (c << 3)) = d;
    }
    __syncthreads();
#pragma unroll 4
    for (int r = 0; r < 32; ++r){
      const float qv = b2f(qs[(r << 8) + t]);
      qd += qv * wp[moff + r];
      const u16* row = kv + r * 272;
#pragma unroll
      for (int kk = 0; kk < 7; ++kk)
        att[kk] += qv * b2f(row[bi[kk]]);
    }
  }

  // ---- positional term + scale + softmax over the 7-window ----
  const float locw = -1.f + (2.f / 8191.f) * (float)wq;
  float mx = -1e30f;
#pragma unroll
  for (int kk = 0; kk < 7; ++kk){
    int wr = wq + kk - 3;
    wr = wr < 0 ? -wr : (wr > 8191 ? 16382 - wr : wr);
    const float lr = -1.f + (2.f / 8191.f) * (float)wr;
    att[kk] = 0.125f * (att[kk] + (locw - lr) * qd);
    mx = fmaxf(mx, att[kk]);
  }
  float p[7]; float ssum = 0.f;
#pragma unroll
  for (int kk = 0; kk < 7; ++kk){ p[kk] = __expf(att[kk] - mx); ssum += p[kk]; }
  const float inv = 1.f / ssum;
#pragma unroll
  for (int kk = 0; kk < 7; ++kk) p[kk] *= inv;

  const float r1 = r1p[0];
  const float r2 = r2p[0];

  // ---- phase B: d-chunks of 32: stage v (+f once), PV + conv, store out ----
  for (int ch = 0; ch < 2; ++ch){
    const int moff = ch << 5;
    __syncthreads();
#pragma unroll
    for (int k = 0; k < 4; ++k){
      const int id = t + (k << 8);
      const int r = id >> 5, c = id & 31;
      int wc = base + (c << 3); if (wc > 8184) wc = 8184;
      const uint4 d = *(const uint4*)(qkvt + (((size_t)(bm + 512 + (h << 6) + moff + r)) << 13) + wc);
      *(uint4*)(kv + r * 272 + (c << 3)) = d;
    }
    if (t < 64){
      const int r = t >> 1, c = 32 + (t & 1);
      int wc = base + (c << 3); if (wc > 8184) wc = 8184;
      const uint4 d = *(const uint4*)(qkvt + (((size_t)(bm + 512 + (h << 6) + moff + r)) << 13) + wc);
      *(uint4*)(kv + r * 272 + (c << 3)) = d;
    }
    if (ch == 0){
#pragma unroll
      for (int k = 0; k < 2; ++k){           // f-tile: 16 rows x 32 chunks
        const int id = t + (k << 8);
        const int r = id >> 5, c = id & 31;
        const uint4 d = *(const uint4*)(qkvt + (((size_t)(bm + 768 + (h << 4) + r)) << 13) + (wt << 8) + (c << 3));
        *(uint4*)(fs + (r << 8) + (c << 3)) = d;
      }
    }
    __syncthreads();
#pragma unroll 4
    for (int r = 0; r < 32; ++r){
      const u16* row = kv + r * 272;
      float o = 0.f;
#pragma unroll
      for (int kk = 0; kk < 7; ++kk)
        o += p[kk] * b2f(row[bi[kk]]);
      const int d = moff + r;
      const float fvv = b2f(fs[((d >> 2) << 8) + t]);
      const float oc = depw[(h << 6) + d] * fvv + depb[(h << 6) + d];
      out[(((size_t)((b << 8) + (h << 6) + d)) << 13) + wq] = r1 * o + r2 * oc;
    }
  }
}

// ---------------------------------------------------------------------------
// launch
// ---------------------------------------------------------------------------
extern "C" void kernel_launch(void* const* d_in, const int* in_sizes, int n_in,
                              void* d_out, int out_size, void* d_ws, size_t ws_size,
                              hipStream_t stream){
  (void)in_sizes; (void)n_in; (void)out_size; (void)ws_size;
  const float* x    = (const float*)d_in[0];
  const float* w1   = (const float*)d_in[1];
  const float* b1   = (const float*)d_in[2];
  const float* w2   = (const float*)d_in[3];
  const float* b2   = (const float*)d_in[4];
  const float* w3   = (const float*)d_in[5];
  const float* b3   = (const float*)d_in[6];
  const float* wp   = (const float*)d_in[7];
  // d_in[8] = bp : cancels analytically, unused
  const float* fcw  = (const float*)d_in[9];
  const float* depw = (const float*)d_in[10];
  const float* depb = (const float*)d_in[11];
  const float* r1p  = (const float*)d_in[12];
  const float* r2p  = (const float*)d_in[13];
  float* out = (float*)d_out;

  char* ws = (char*)d_ws;
  u16*   Wall = (u16*)(ws);                  // 896*256*2 = 458,752 B
  float* ball = (float*)(ws + 458752);       // 896*4     =   3,584 B
  u16*   qkvt = (u16*)(ws + 462336);         // 4*832*8192*2 = 54,525,952 B (channel-major [b][m][w])

  k_build<<<dim3(896, 1, 1), 256, 0, stream>>>(w1, b1, w2, b2, w3, b3, fcw, Wall, ball);
  gemm_qkv<<<dim3(7, 256, 1), 256, 0, stream>>>(Wall, ball, x, qkvt);
  attn_out<<<dim3(32, 4, 4), 256, 0, stream>>>(qkvt, wp, depw, depb, r1p, r2p, out);
}